// Round 2
// baseline (564.945 us; speedup 1.0000x reference)
//
#include <hip/hip_runtime.h>

// One block = 256 Gaussians. Memory-bound element-wise op.
// Strided global traffic (scaling stride-12B reads, cov3d stride-36B writes,
// color stride-12B writes) is staged through LDS so every global access is a
// fully-coalesced float4. features[:,0,:] gather stays strided (layout-imposed
// 64B-sector fetch), loaded as one aligned float4.
// Output: cov3d(9N) | cov2d(4N) | color(3N) | opacity(N), all f32.

#define TPB 256

__global__ __launch_bounds__(TPB) void gauss_props_kernel(
    const float*  __restrict__ scaling_raw,   // (N,3)
    const float4* __restrict__ rotation,      // (N,4)
    const float*  __restrict__ opacity_raw,   // (N,1)
    const float*  __restrict__ features,      // (N,16,3)
    float* __restrict__ out, int N)
{
    __shared__ float s_scal[TPB * 3];  // 3 KB
    __shared__ float s_cov [TPB * 9];  // 9 KB
    __shared__ float s_col [TPB * 3];  // 3 KB

    const int tid = threadIdx.x;
    const int block_base = blockIdx.x * TPB;
    const int n = block_base + tid;
    const bool valid = n < N;

    const size_t N3 = (size_t)3 * N;
    const size_t N9 = (size_t)9 * N;

    // ---- cooperative coalesced load of this block's scaling rows ----
    // floats [3*block_base, 3*block_base + 768) -> 192 float4 (16B aligned:
    // 3*256*b = 768b divisible by 4).
    if (tid < 192) {
        size_t f = (size_t)3 * block_base + 4 * (size_t)tid;
        if (f + 3 < N3) {
            *reinterpret_cast<float4*>(&s_scal[4 * tid]) =
                *reinterpret_cast<const float4*>(&scaling_raw[f]);
        } else {
            #pragma unroll
            for (int e = 0; e < 4; ++e)
                s_scal[4 * tid + e] = (f + e < N3) ? scaling_raw[f + e] : 0.f;
        }
    }
    __syncthreads();

    float var = 0.f, opac = 0.f;
    if (valid) {
        // --- quaternion -> rotation matrix ---
        float4 q = rotation[n];
        float inv = rsqrtf(q.x * q.x + q.y * q.y + q.z * q.z + q.w * q.w);
        float w = q.x * inv, x = q.y * inv, y = q.z * inv, z = q.w * inv;

        float xx = x * x, yy = y * y, zz = z * z;
        float wx = w * x, wy = w * y, wz = w * z;
        float xy = x * y, xz = x * z, yz = y * z;

        float R[3][3];
        R[0][0] = 1.f - 2.f * (yy + zz); R[0][1] = 2.f * (xy - wz); R[0][2] = 2.f * (xz + wy);
        R[1][0] = 2.f * (xy + wz); R[1][1] = 1.f - 2.f * (xx + zz); R[1][2] = 2.f * (yz - wx);
        R[2][0] = 2.f * (xz - wy); R[2][1] = 2.f * (yz + wx); R[2][2] = 1.f - 2.f * (xx + yy);

        // --- sigma^2 = exp(2*scaling) (from LDS stage) ---
        float s0 = __expf(2.f * s_scal[3 * tid + 0]);
        float s1 = __expf(2.f * s_scal[3 * tid + 1]);
        float s2 = __expf(2.f * s_scal[3 * tid + 2]);

        // --- cov3d = R diag(s) R^T, staged into LDS for coalesced writeback ---
        #pragma unroll
        for (int i = 0; i < 3; ++i) {
            #pragma unroll
            for (int k = 0; k < 3; ++k) {
                float c = R[i][0] * R[k][0] * s0 + R[i][1] * R[k][1] * s1
                        + R[i][2] * R[k][2] * s2;
                s_cov[9 * tid + 3 * i + k] = c;
                if (i == k) var += c;
            }
        }
        var *= (1.f / 3.f);

        // --- opacity = sigmoid ---
        opac = 1.f / (1.f + __expf(-opacity_raw[n]));

        // --- color = features[n,0,:] (aligned float4, 4th lane unused) ---
        float4 c4 = *reinterpret_cast<const float4*>(&features[(size_t)48 * n]);
        s_col[3 * tid + 0] = c4.x;
        s_col[3 * tid + 1] = c4.y;
        s_col[3 * tid + 2] = c4.z;
    }
    __syncthreads();

    // ---- coalesced float4 writeback: cov3d (576 float4 / block) ----
    {
        size_t base_f = (size_t)9 * block_base;   // float offset in cov3d region
        for (int k = tid; k < (TPB * 9) / 4; k += TPB) {
            size_t f = base_f + 4 * (size_t)k;
            if (f + 3 < N9) {
                *reinterpret_cast<float4*>(&out[f]) =
                    *reinterpret_cast<const float4*>(&s_cov[4 * k]);
            } else {
                #pragma unroll
                for (int e = 0; e < 4; ++e)
                    if (f + e < N9) out[f + e] = s_cov[4 * k + e];
            }
        }
    }

    // ---- coalesced float4 writeback: color (192 float4 / block) ----
    {
        float* out_color = out + 13 * (size_t)N;
        size_t base_f = (size_t)3 * block_base;
        if (tid < 192) {
            size_t f = base_f + 4 * (size_t)tid;
            if (f + 3 < N3) {
                *reinterpret_cast<float4*>(&out_color[f]) =
                    *reinterpret_cast<const float4*>(&s_col[4 * tid]);
            } else {
                #pragma unroll
                for (int e = 0; e < 4; ++e)
                    if (f + e < N3) out_color[f + e] = s_col[4 * tid + e];
            }
        }
    }

    // ---- direct coalesced writes: cov2d (float4/lane), opacity (dword) ----
    if (valid) {
        float4 cv2 = make_float4(var, 0.f, 0.f, var);
        *reinterpret_cast<float4*>(&out[N9 + 4 * (size_t)n]) = cv2;  // 16B aligned: 9N%4==0
        out[16 * (size_t)N + n] = opac;
    }
}

extern "C" void kernel_launch(void* const* d_in, const int* in_sizes, int n_in,
                              void* d_out, int out_size, void* d_ws, size_t ws_size,
                              hipStream_t stream) {
    const float*  scaling  = (const float*)d_in[1];
    const float4* rotation = (const float4*)d_in[2];
    const float*  opacity  = (const float*)d_in[3];
    const float*  features = (const float*)d_in[4];
    float* out = (float*)d_out;

    int N = in_sizes[3]; // opacity_raw has N elements
    int blocks = (N + TPB - 1) / TPB;
    gauss_props_kernel<<<blocks, TPB, 0, stream>>>(scaling, rotation, opacity,
                                                   features, out, N);
}